// Round 1
// baseline (2845.502 us; speedup 1.0000x reference)
//
#include <hip/hip_runtime.h>
#include <math.h>

// GatingNetwork router on MI355X (gfx950).
// h = relu(x@W1 + b1); logits = h@W2 + b2; top2 + softmax gates; balance loss.
// fp32 vector-ALU compute (no fp32 MFMA on CDNA4); compute-bound floor ~874us.
// Output layout (float32): [0,2N) top2 indices (as float), [2N,4N) gates, [4N] loss.

constexpr int K   = 2048;  // input dim
constexpr int H   = 256;   // hidden dim
constexpr int E   = 64;    // experts
constexpr int T   = 64;    // tokens per block
constexpr int KC  = 32;    // k-chunk
constexpr int XSS = 68;    // xs row stride (floats); 272B = 16B-aligned
constexpr int HSS = 260;   // hs row stride; 1040B = 16B-aligned
constexpr int LSS = 65;    // ls row stride (scalar access only)

struct P1 { float xs[KC][XSS]; float ws[KC][H]; };   // 8704 + 32768 B
struct P2 { float hs[32][HSS]; float ls[32][LSS]; }; // 33280 + 8320 B
union __align__(16) SMem { P1 p1; P2 p2; };

__global__ __launch_bounds__(256, 3)
void gating_fused(const float* __restrict__ x,
                  const float* __restrict__ W1,
                  const float* __restrict__ b1,
                  const float* __restrict__ W2,
                  const float* __restrict__ b2,
                  float* __restrict__ out,
                  float* __restrict__ gcnt,
                  float* __restrict__ gprob,
                  int Ntok)
{
    __shared__ SMem sm;
    __shared__ float s_cnt[E];
    __shared__ float s_pe[4][E];
    __shared__ float s_m1[32];
    __shared__ float s_rZ[32];

    const int tid  = threadIdx.x;
    const int jl   = tid & 31;        // 32 j-lanes: 8 cols each -> 256 cols
    const int j0   = jl * 8;
    const int tgrp = tid >> 5;        // 8 t-groups: 8 tokens each -> 64 tokens
    const int t0g  = tgrp * 8;
    const long long tok0 = (long long)blockIdx.x * T;

    float acc[8][8];
#pragma unroll
    for (int a = 0; a < 8; ++a)
#pragma unroll
        for (int b = 0; b < 8; ++b) acc[a][b] = 0.f;

    // ---------------- Phase 1: h = x @ W1 (accumulate in registers) ----------
    for (int k0 = 0; k0 < K; k0 += KC) {
        // stage x tile transposed: xs[k][t] = x[tok0+t][k0+k]
#pragma unroll
        for (int it = 0; it < 2; ++it) {
            int idx = it * 256 + tid;
            int t   = idx >> 3;
            int c   = (idx & 7) * 4;
            float4 v = *(const float4*)&x[(tok0 + t) * (long long)K + k0 + c];
            sm.p1.xs[c + 0][t] = v.x;
            sm.p1.xs[c + 1][t] = v.y;
            sm.p1.xs[c + 2][t] = v.z;
            sm.p1.xs[c + 3][t] = v.w;
        }
        // stage W1 tile: ws[r][c] = W1[(k0+r)*H + c]
#pragma unroll
        for (int it = 0; it < 8; ++it) {
            int idx = it * 256 + tid;
            int r   = idx >> 6;
            int c   = (idx & 63) * 4;
            *(float4*)&sm.p1.ws[r][c] = *(const float4*)&W1[(long long)(k0 + r) * H + c];
        }
        __syncthreads();
#pragma unroll 8
        for (int k = 0; k < KC; ++k) {
            float4 xa = *(const float4*)&sm.p1.xs[k][t0g];
            float4 xb = *(const float4*)&sm.p1.xs[k][t0g + 4];
            float4 wa = *(const float4*)&sm.p1.ws[k][j0];
            float4 wb = *(const float4*)&sm.p1.ws[k][j0 + 4];
            float xv[8] = {xa.x, xa.y, xa.z, xa.w, xb.x, xb.y, xb.z, xb.w};
            float wv[8] = {wa.x, wa.y, wa.z, wa.w, wb.x, wb.y, wb.z, wb.w};
#pragma unroll
            for (int a = 0; a < 8; ++a)
#pragma unroll
                for (int b = 0; b < 8; ++b)
                    acc[a][b] = fmaf(xv[a], wv[b], acc[a][b]);
        }
        __syncthreads();
    }

    float bb[8];
    {
        float4 b0 = *(const float4*)&b1[j0];
        float4 b4 = *(const float4*)&b1[j0 + 4];
        bb[0]=b0.x; bb[1]=b0.y; bb[2]=b0.z; bb[3]=b0.w;
        bb[4]=b4.x; bb[5]=b4.y; bb[6]=b4.z; bb[7]=b4.w;
    }
    const int el  = tid & 63;
    const int tg2 = tid >> 6;
    const float b2v = b2[el];

    if (tid < E) s_cnt[tid] = 0.f;
    float probacc = 0.f;

    // ---------- Phase 2: logits / top2 / gates / stats, 32 tokens per half ----
    for (int half = 0; half < 2; ++half) {
        if ((tgrp >> 2) == half) {
            int lt0 = t0g - half * 32;
#pragma unroll
            for (int a = 0; a < 8; ++a) {
                float4 h0, h1;
                h0.x = fmaxf(acc[a][0] + bb[0], 0.f);
                h0.y = fmaxf(acc[a][1] + bb[1], 0.f);
                h0.z = fmaxf(acc[a][2] + bb[2], 0.f);
                h0.w = fmaxf(acc[a][3] + bb[3], 0.f);
                h1.x = fmaxf(acc[a][4] + bb[4], 0.f);
                h1.y = fmaxf(acc[a][5] + bb[5], 0.f);
                h1.z = fmaxf(acc[a][6] + bb[6], 0.f);
                h1.w = fmaxf(acc[a][7] + bb[7], 0.f);
                *(float4*)&sm.p2.hs[lt0 + a][j0]     = h0;
                *(float4*)&sm.p2.hs[lt0 + a][j0 + 4] = h1;
            }
        }
        __syncthreads();

        // logits: thread (el, tg2) -> expert el, 8 tokens
        {
            float lg[8];
#pragma unroll
            for (int a = 0; a < 8; ++a) lg[a] = b2v;
            for (int r = 0; r < H; r += 4) {
                float w0 = W2[(r + 0) * E + el];
                float w1 = W2[(r + 1) * E + el];
                float w2v = W2[(r + 2) * E + el];
                float w3 = W2[(r + 3) * E + el];
#pragma unroll
                for (int a = 0; a < 8; ++a) {
                    float4 h4 = *(const float4*)&sm.p2.hs[tg2 * 8 + a][r];
                    lg[a] = fmaf(h4.x, w0,  lg[a]);
                    lg[a] = fmaf(h4.y, w1,  lg[a]);
                    lg[a] = fmaf(h4.z, w2v, lg[a]);
                    lg[a] = fmaf(h4.w, w3,  lg[a]);
                }
            }
#pragma unroll
            for (int a = 0; a < 8; ++a) sm.p2.ls[tg2 * 8 + a][el] = lg[a];
        }
        __syncthreads();

        // top-2 + gates + softmax stats, one thread per token
        if (tid < 32) {
            int t = tid;
            float m1 = -3.4e38f, m2 = -3.4e38f;
            int i1 = 0, i2 = 0;
            for (int i = 0; i < E; ++i) {
                float v = sm.p2.ls[t][i];
                if (v > m1)      { m2 = m1; i2 = i1; m1 = v; i1 = i; }
                else if (v > m2) { m2 = v;  i2 = i; }
            }
            float Z = 0.f;
            for (int i = 0; i < E; ++i) Z += expf(sm.p2.ls[t][i] - m1);
            long long gt = tok0 + half * 32 + t;
            out[2 * gt]     = (float)i1;
            out[2 * gt + 1] = (float)i2;
            float ed = expf(m2 - m1);
            float g1 = 1.f / (1.f + ed);
            out[2 * (long long)Ntok + 2 * gt]     = g1;
            out[2 * (long long)Ntok + 2 * gt + 1] = ed * g1;
            s_m1[t] = m1;
            s_rZ[t] = 1.f / Z;
            atomicAdd(&s_cnt[i1], 1.f);
            atomicAdd(&s_cnt[i2], 1.f);
        }
        __syncthreads();

        // router-prob partial sums per expert
#pragma unroll
        for (int a = 0; a < 8; ++a) {
            int lt = tg2 * 8 + a;
            probacc += expf(sm.p2.ls[lt][el] - s_m1[lt]) * s_rZ[lt];
        }
        __syncthreads();
    }

    s_pe[tg2][el] = probacc;
    __syncthreads();
    if (tid < E) {
        float p = s_pe[0][tid] + s_pe[1][tid] + s_pe[2][tid] + s_pe[3][tid];
        atomicAdd(&gprob[tid], p);
        atomicAdd(&gcnt[tid], s_cnt[tid]);
    }
}

__global__ void balance_loss_k(const float* __restrict__ gcnt,
                               const float* __restrict__ gprob,
                               float* __restrict__ out, int Ntok)
{
    int t = threadIdx.x;  // 64 threads
    float v = gcnt[t] * gprob[t];
#pragma unroll
    for (int off = 32; off > 0; off >>= 1) v += __shfl_down(v, off, 64);
    if (t == 0) {
        double invN = 1.0 / (double)Ntok;
        out[4 * (long long)Ntok] = (float)((double)E * (double)v * invN * invN);
    }
}

extern "C" void kernel_launch(void* const* d_in, const int* in_sizes, int n_in,
                              void* d_out, int out_size, void* d_ws, size_t ws_size,
                              hipStream_t stream)
{
    const float* x  = (const float*)d_in[0];
    const float* W1 = (const float*)d_in[1];
    const float* b1 = (const float*)d_in[2];
    const float* W2 = (const float*)d_in[3];
    const float* b2 = (const float*)d_in[4];
    float* outp = (float*)d_out;
    const int Ntok = in_sizes[0] / K;

    float* gcnt  = (float*)d_ws;
    float* gprob = gcnt + E;
    hipMemsetAsync(d_ws, 0, 2 * E * sizeof(float), stream);

    gating_fused<<<Ntok / T, 256, 0, stream>>>(x, W1, b1, W2, b2, outp, gcnt, gprob, Ntok);
    balance_loss_k<<<1, 64, 0, stream>>>(gcnt, gprob, outp, Ntok);
}